// Round 1
// baseline (2009.393 us; speedup 1.0000x reference)
//
#include <hip/hip_runtime.h>
#include <hip/hip_bf16.h>

constexpr int NN = 100000;   // nodes
constexpr int NE = 3200000;  // edges

// ---------------------------------------------------------------------------
// Kernel 1: y1[n][o] = sum_k x[n][k] * W1_rel[o][k]   (N x 64 -> N x 32)
// One thread per node; x row held in 64 VGPRs; W reads are wave-uniform
// (compiler emits s_load -> SGPR-operand FMAs).
// ---------------------------------------------------------------------------
__global__ __launch_bounds__(256) void k_transform1(
    const float* __restrict__ x, const float* __restrict__ W1_rel,
    float* __restrict__ y1)
{
    int n = blockIdx.x * 256 + threadIdx.x;
    if (n >= NN) return;
    float xr[64];
    const float4* xrow = reinterpret_cast<const float4*>(x + (size_t)n * 64);
#pragma unroll
    for (int i = 0; i < 16; ++i) {
        float4 v = xrow[i];
        xr[4*i+0] = v.x; xr[4*i+1] = v.y; xr[4*i+2] = v.z; xr[4*i+3] = v.w;
    }
    float4* out = reinterpret_cast<float4*>(y1 + (size_t)n * 32);
#pragma unroll
    for (int og = 0; og < 8; ++og) {
        float a[4];
#pragma unroll
        for (int j = 0; j < 4; ++j) {
            const float* wrow = W1_rel + (og * 4 + j) * 64;
            float s = 0.f;
#pragma unroll
            for (int k = 0; k < 64; ++k) s += xr[k] * wrow[k];
            a[j] = s;
        }
        float4 v; v.x = a[0]; v.y = a[1]; v.z = a[2]; v.w = a[3];
        out[og] = v;
    }
}

// ---------------------------------------------------------------------------
// Kernel 2: edge pass 1. 8 threads per edge, each handles 4 consecutive
// features: gather float4 of y1[src], scale by w, atomically add into agg1[dst].
// ---------------------------------------------------------------------------
__global__ __launch_bounds__(256) void k_edge1(
    const int* __restrict__ ei, const float* __restrict__ ew,
    const float* __restrict__ y1, float* __restrict__ agg1)
{
    int idx = blockIdx.x * 256 + threadIdx.x;     // e*8 + g, max 25.6M
    if (idx >= NE * 8) return;
    int e = idx >> 3;
    int g = idx & 7;
    int s = ei[e];
    int d = ei[NE + e];
    float w = ew[e];
    float4 v = *reinterpret_cast<const float4*>(y1 + (size_t)s * 32 + g * 4);
    float* a = agg1 + (size_t)d * 32 + g * 4;
    unsafeAtomicAdd(a + 0, v.x * w);
    unsafeAtomicAdd(a + 1, v.y * w);
    unsafeAtomicAdd(a + 2, v.z * w);
    unsafeAtomicAdd(a + 3, v.w * w);
}

// ---------------------------------------------------------------------------
// Kernel 3: h = relu(agg1 + b1 + x @ W1_root.T), then immediately
// y2 = h @ W2_rel.T, r2 = h @ W2_root.T.  h never hits memory.
// ---------------------------------------------------------------------------
__global__ __launch_bounds__(256) void k_node1(
    const float* __restrict__ x, const float* __restrict__ agg1,
    const float* __restrict__ W1_root, const float* __restrict__ b1,
    const float* __restrict__ W2_rel, const float* __restrict__ W2_root,
    float* __restrict__ y2, float* __restrict__ r2)
{
    int n = blockIdx.x * 256 + threadIdx.x;
    if (n >= NN) return;
    float xr[64];
    const float4* xrow = reinterpret_cast<const float4*>(x + (size_t)n * 64);
#pragma unroll
    for (int i = 0; i < 16; ++i) {
        float4 v = xrow[i];
        xr[4*i+0] = v.x; xr[4*i+1] = v.y; xr[4*i+2] = v.z; xr[4*i+3] = v.w;
    }
    float h[32];
    const float4* arow = reinterpret_cast<const float4*>(agg1 + (size_t)n * 32);
#pragma unroll
    for (int og = 0; og < 8; ++og) {
        float4 v = arow[og];
        h[og*4+0] = v.x; h[og*4+1] = v.y; h[og*4+2] = v.z; h[og*4+3] = v.w;
    }
#pragma unroll
    for (int o = 0; o < 32; ++o) {
        const float* wrow = W1_root + o * 64;
        float s = 0.f;
#pragma unroll
        for (int k = 0; k < 64; ++k) s += xr[k] * wrow[k];
        float t = h[o] + b1[o] + s;
        h[o] = t > 0.f ? t : 0.f;
    }
    // layer-2 transforms
    float o2[8], o3[8];
#pragma unroll
    for (int j = 0; j < 8; ++j) {
        const float* wr = W2_rel  + j * 32;
        const float* wo = W2_root + j * 32;
        float s0 = 0.f, s1 = 0.f;
#pragma unroll
        for (int c = 0; c < 32; ++c) { s0 += h[c] * wr[c]; s1 += h[c] * wo[c]; }
        o2[j] = s0; o3[j] = s1;
    }
    float4* y2o = reinterpret_cast<float4*>(y2 + (size_t)n * 8);
    float4* r2o = reinterpret_cast<float4*>(r2 + (size_t)n * 8);
    float4 v0, v1;
    v0.x=o2[0]; v0.y=o2[1]; v0.z=o2[2]; v0.w=o2[3]; y2o[0]=v0;
    v1.x=o2[4]; v1.y=o2[5]; v1.z=o2[6]; v1.w=o2[7]; y2o[1]=v1;
    v0.x=o3[0]; v0.y=o3[1]; v0.z=o3[2]; v0.w=o3[3]; r2o[0]=v0;
    v1.x=o3[4]; v1.y=o3[5]; v1.z=o3[6]; v1.w=o3[7]; r2o[1]=v1;
}

// ---------------------------------------------------------------------------
// Kernel 4: edge pass 2. 2 threads per edge, 4 features each (H2=8).
// ---------------------------------------------------------------------------
__global__ __launch_bounds__(256) void k_edge2(
    const int* __restrict__ ei, const float* __restrict__ ew,
    const float* __restrict__ y2, float* __restrict__ agg2)
{
    int idx = blockIdx.x * 256 + threadIdx.x;     // e*2 + g, max 6.4M
    if (idx >= NE * 2) return;
    int e = idx >> 1;
    int g = idx & 1;
    int s = ei[e];
    int d = ei[NE + e];
    float w = ew[e];
    float4 v = *reinterpret_cast<const float4*>(y2 + (size_t)s * 8 + g * 4);
    float* a = agg2 + (size_t)d * 8 + g * 4;
    unsafeAtomicAdd(a + 0, v.x * w);
    unsafeAtomicAdd(a + 1, v.y * w);
    unsafeAtomicAdd(a + 2, v.z * w);
    unsafeAtomicAdd(a + 3, v.w * w);
}

// ---------------------------------------------------------------------------
// Kernel 5: h2 = agg2 + b2 + r2; embedding = log_softmax(h2);
// out = relu([embedding, x1] @ W_lin.T + b_lin)
// ---------------------------------------------------------------------------
__global__ __launch_bounds__(256) void k_final(
    const float* __restrict__ agg2, const float* __restrict__ r2,
    const float* __restrict__ x1, const float* __restrict__ b2,
    const float* __restrict__ W_lin, const float* __restrict__ b_lin,
    float* __restrict__ outv, float* __restrict__ emb)
{
    int n = blockIdx.x * 256 + threadIdx.x;
    if (n >= NN) return;
    const float4* arow = reinterpret_cast<const float4*>(agg2 + (size_t)n * 8);
    const float4* rrow = reinterpret_cast<const float4*>(r2   + (size_t)n * 8);
    float h2[8];
    {
        float4 a0 = arow[0], a1 = arow[1], r0 = rrow[0], r1 = rrow[1];
        h2[0]=a0.x+r0.x+b2[0]; h2[1]=a0.y+r0.y+b2[1];
        h2[2]=a0.z+r0.z+b2[2]; h2[3]=a0.w+r0.w+b2[3];
        h2[4]=a1.x+r1.x+b2[4]; h2[5]=a1.y+r1.y+b2[5];
        h2[6]=a1.z+r1.z+b2[6]; h2[7]=a1.w+r1.w+b2[7];
    }
    float m = h2[0];
#pragma unroll
    for (int j = 1; j < 8; ++j) m = fmaxf(m, h2[j]);
    float sum = 0.f;
#pragma unroll
    for (int j = 0; j < 8; ++j) sum += __expf(h2[j] - m);
    float lse = __logf(sum);
    float eb[8];
#pragma unroll
    for (int j = 0; j < 8; ++j) eb[j] = h2[j] - m - lse;
    float4* eo = reinterpret_cast<float4*>(emb + (size_t)n * 8);
    float4 v0, v1;
    v0.x=eb[0]; v0.y=eb[1]; v0.z=eb[2]; v0.w=eb[3]; eo[0]=v0;
    v1.x=eb[4]; v1.y=eb[5]; v1.z=eb[6]; v1.w=eb[7]; eo[1]=v1;
    float acc = b_lin[0] + x1[n] * W_lin[8];
#pragma unroll
    for (int j = 0; j < 8; ++j) acc += eb[j] * W_lin[j];
    outv[n] = acc > 0.f ? acc : 0.f;
}

// ---------------------------------------------------------------------------
extern "C" void kernel_launch(void* const* d_in, const int* in_sizes, int n_in,
                              void* d_out, int out_size, void* d_ws, size_t ws_size,
                              hipStream_t stream) {
    const float* x      = (const float*)d_in[0];
    const int*   ei     = (const int*)  d_in[1];
    const float* ew     = (const float*)d_in[2];
    const float* x1     = (const float*)d_in[3];
    const float* W1_rel = (const float*)d_in[4];
    const float* b1     = (const float*)d_in[5];
    const float* W1_root= (const float*)d_in[6];
    const float* W2_rel = (const float*)d_in[7];
    const float* b2     = (const float*)d_in[8];
    const float* W2_root= (const float*)d_in[9];
    const float* W_lin  = (const float*)d_in[10];
    const float* b_lin  = (const float*)d_in[11];

    float* ws   = (float*)d_ws;
    float* y1   = ws;                        // N*32
    float* agg1 = y1   + (size_t)NN * 32;    // N*32
    float* y2   = agg1 + (size_t)NN * 32;    // N*8
    float* r2   = y2   + (size_t)NN * 8;     // N*8
    float* agg2 = r2   + (size_t)NN * 8;     // N*8

    float* outv = (float*)d_out;             // N  (output 0)
    float* emb  = outv + NN;                 // N*8 (output 1)

    hipMemsetAsync(agg1, 0, (size_t)NN * 32 * sizeof(float), stream);
    hipMemsetAsync(agg2, 0, (size_t)NN * 8  * sizeof(float), stream);

    int nb = (NN + 255) / 256;
    k_transform1<<<nb, 256, 0, stream>>>(x, W1_rel, y1);
    k_edge1<<<(NE * 8 + 255) / 256, 256, 0, stream>>>(ei, ew, y1, agg1);
    k_node1<<<nb, 256, 0, stream>>>(x, agg1, W1_root, b1, W2_rel, W2_root, y2, r2);
    k_edge2<<<(NE * 2 + 255) / 256, 256, 0, stream>>>(ei, ew, y2, agg2);
    k_final<<<nb, 256, 0, stream>>>(agg2, r2, x1, b2, W_lin, b_lin, outv, emb);
}

// Round 2
// 791.176 us; speedup vs baseline: 2.5398x; 2.5398x over previous
//
#include <hip/hip_runtime.h>
#include <hip/hip_bf16.h>

constexpr int NN = 100000;   // nodes
constexpr int NE = 3200000;  // edges

// ---------------------------------------------------------------------------
// CSR build: histogram of destinations
// ---------------------------------------------------------------------------
__global__ __launch_bounds__(256) void k_hist(
    const int* __restrict__ ei, int* __restrict__ counts)
{
    int e = blockIdx.x * 256 + threadIdx.x;
    if (e >= NE) return;
    atomicAdd(counts + ei[NE + e], 1);
}

// ---------------------------------------------------------------------------
// Single-block exclusive scan of counts[NN] -> rowptr[NN+1], plus cursor copy.
// 1024 threads, each owns a contiguous chunk.
// ---------------------------------------------------------------------------
__global__ __launch_bounds__(1024) void k_scan(
    const int* __restrict__ counts, int* __restrict__ rowptr,
    int* __restrict__ cursor)
{
    __shared__ int lds[1024];
    int t = threadIdx.x;
    const int chunk = (NN + 1023) / 1024;   // 98
    int base = t * chunk;
    int end  = base + chunk; if (end > NN) end = NN;
    int s = 0;
    for (int i = base; i < end; ++i) s += counts[i];
    lds[t] = s;
    __syncthreads();
    // Hillis-Steele inclusive scan
    for (int off = 1; off < 1024; off <<= 1) {
        int v = (t >= off) ? lds[t - off] : 0;
        __syncthreads();
        lds[t] += v;
        __syncthreads();
    }
    int run = (t == 0) ? 0 : lds[t - 1];
    for (int i = base; i < end; ++i) {
        rowptr[i] = run;
        cursor[i] = run;
        run += counts[i];
    }
    if (end == NN && base < NN + 1) rowptr[NN] = run;
    if (t == 1023) rowptr[NN] = lds[1023];
}

// ---------------------------------------------------------------------------
// Scatter edges into dst-sorted order: packed[pos] = {src, bits(weight)}
// ---------------------------------------------------------------------------
__global__ __launch_bounds__(256) void k_scatter(
    const int* __restrict__ ei, const float* __restrict__ ew,
    int* __restrict__ cursor, int2* __restrict__ packed)
{
    int e = blockIdx.x * 256 + threadIdx.x;
    if (e >= NE) return;
    int d = ei[NE + e];
    int pos = atomicAdd(cursor + d, 1);
    int2 p; p.x = ei[e]; p.y = __float_as_int(ew[e]);
    packed[pos] = p;
}

// ---------------------------------------------------------------------------
// y1 = x @ W1_rel.T   (N x 64 -> N x 32); one thread per node.
// ---------------------------------------------------------------------------
__global__ __launch_bounds__(256) void k_transform1(
    const float* __restrict__ x, const float* __restrict__ W1_rel,
    float* __restrict__ y1)
{
    int n = blockIdx.x * 256 + threadIdx.x;
    if (n >= NN) return;
    float xr[64];
    const float4* xrow = reinterpret_cast<const float4*>(x + (size_t)n * 64);
#pragma unroll
    for (int i = 0; i < 16; ++i) {
        float4 v = xrow[i];
        xr[4*i+0] = v.x; xr[4*i+1] = v.y; xr[4*i+2] = v.z; xr[4*i+3] = v.w;
    }
    float4* out = reinterpret_cast<float4*>(y1 + (size_t)n * 32);
#pragma unroll
    for (int og = 0; og < 8; ++og) {
        float a[4];
#pragma unroll
        for (int j = 0; j < 4; ++j) {
            const float* wrow = W1_rel + (og * 4 + j) * 64;
            float s = 0.f;
#pragma unroll
            for (int k = 0; k < 64; ++k) s += xr[k] * wrow[k];
            a[j] = s;
        }
        float4 v; v.x = a[0]; v.y = a[1]; v.z = a[2]; v.w = a[3];
        out[og] = v;
    }
}

// ---------------------------------------------------------------------------
// Gather-reduce pass 1: 8 lanes per dst, one float4 feature-group each.
// Edge-pair loads broadcast across the 8 lanes; y1-row gathers coalesce
// to a full 128B row. No atomics.
// ---------------------------------------------------------------------------
__global__ __launch_bounds__(256) void k_reduce1(
    const int* __restrict__ rowptr, const int2* __restrict__ packed,
    const float* __restrict__ y1, float* __restrict__ agg1)
{
    int idx = blockIdx.x * 256 + threadIdx.x;   // d*8 + g
    if (idx >= NN * 8) return;
    int d = idx >> 3;
    int g = idx & 7;
    int beg = rowptr[d], end = rowptr[d + 1];
    float ax = 0.f, ay = 0.f, az = 0.f, aw = 0.f;
    for (int e = beg; e < end; ++e) {
        int2 p = packed[e];
        float w = __int_as_float(p.y);
        float4 v = *reinterpret_cast<const float4*>(y1 + (size_t)p.x * 32 + g * 4);
        ax += v.x * w; ay += v.y * w; az += v.z * w; aw += v.w * w;
    }
    float4 o; o.x = ax; o.y = ay; o.z = az; o.w = aw;
    *reinterpret_cast<float4*>(agg1 + (size_t)d * 32 + g * 4) = o;
}

// ---------------------------------------------------------------------------
// h = relu(agg1 + b1 + x @ W1_root.T); y2 = h @ W2_rel.T; r2 = h @ W2_root.T
// ---------------------------------------------------------------------------
__global__ __launch_bounds__(256) void k_node1(
    const float* __restrict__ x, const float* __restrict__ agg1,
    const float* __restrict__ W1_root, const float* __restrict__ b1,
    const float* __restrict__ W2_rel, const float* __restrict__ W2_root,
    float* __restrict__ y2, float* __restrict__ r2)
{
    int n = blockIdx.x * 256 + threadIdx.x;
    if (n >= NN) return;
    float xr[64];
    const float4* xrow = reinterpret_cast<const float4*>(x + (size_t)n * 64);
#pragma unroll
    for (int i = 0; i < 16; ++i) {
        float4 v = xrow[i];
        xr[4*i+0] = v.x; xr[4*i+1] = v.y; xr[4*i+2] = v.z; xr[4*i+3] = v.w;
    }
    float h[32];
    const float4* arow = reinterpret_cast<const float4*>(agg1 + (size_t)n * 32);
#pragma unroll
    for (int og = 0; og < 8; ++og) {
        float4 v = arow[og];
        h[og*4+0] = v.x; h[og*4+1] = v.y; h[og*4+2] = v.z; h[og*4+3] = v.w;
    }
#pragma unroll
    for (int o = 0; o < 32; ++o) {
        const float* wrow = W1_root + o * 64;
        float s = 0.f;
#pragma unroll
        for (int k = 0; k < 64; ++k) s += xr[k] * wrow[k];
        float t = h[o] + b1[o] + s;
        h[o] = t > 0.f ? t : 0.f;
    }
    float o2[8], o3[8];
#pragma unroll
    for (int j = 0; j < 8; ++j) {
        const float* wr = W2_rel  + j * 32;
        const float* wo = W2_root + j * 32;
        float s0 = 0.f, s1 = 0.f;
#pragma unroll
        for (int c = 0; c < 32; ++c) { s0 += h[c] * wr[c]; s1 += h[c] * wo[c]; }
        o2[j] = s0; o3[j] = s1;
    }
    float4* y2o = reinterpret_cast<float4*>(y2 + (size_t)n * 8);
    float4* r2o = reinterpret_cast<float4*>(r2 + (size_t)n * 8);
    float4 v0, v1;
    v0.x=o2[0]; v0.y=o2[1]; v0.z=o2[2]; v0.w=o2[3]; y2o[0]=v0;
    v1.x=o2[4]; v1.y=o2[5]; v1.z=o2[6]; v1.w=o2[7]; y2o[1]=v1;
    v0.x=o3[0]; v0.y=o3[1]; v0.z=o3[2]; v0.w=o3[3]; r2o[0]=v0;
    v1.x=o3[4]; v1.y=o3[5]; v1.z=o3[6]; v1.w=o3[7]; r2o[1]=v1;
}

// ---------------------------------------------------------------------------
// Gather-reduce pass 2: 2 lanes per dst (8 features).
// ---------------------------------------------------------------------------
__global__ __launch_bounds__(256) void k_reduce2(
    const int* __restrict__ rowptr, const int2* __restrict__ packed,
    const float* __restrict__ y2, float* __restrict__ agg2)
{
    int idx = blockIdx.x * 256 + threadIdx.x;   // d*2 + g
    if (idx >= NN * 2) return;
    int d = idx >> 1;
    int g = idx & 1;
    int beg = rowptr[d], end = rowptr[d + 1];
    float ax = 0.f, ay = 0.f, az = 0.f, aw = 0.f;
    for (int e = beg; e < end; ++e) {
        int2 p = packed[e];
        float w = __int_as_float(p.y);
        float4 v = *reinterpret_cast<const float4*>(y2 + (size_t)p.x * 8 + g * 4);
        ax += v.x * w; ay += v.y * w; az += v.z * w; aw += v.w * w;
    }
    float4 o; o.x = ax; o.y = ay; o.z = az; o.w = aw;
    *reinterpret_cast<float4*>(agg2 + (size_t)d * 8 + g * 4) = o;
}

// ---------------------------------------------------------------------------
// Final: h2 = agg2 + b2 + r2; emb = log_softmax(h2); out = relu([emb,x1]@W_lin.T+b)
// ---------------------------------------------------------------------------
__global__ __launch_bounds__(256) void k_final(
    const float* __restrict__ agg2, const float* __restrict__ r2,
    const float* __restrict__ x1, const float* __restrict__ b2,
    const float* __restrict__ W_lin, const float* __restrict__ b_lin,
    float* __restrict__ outv, float* __restrict__ emb)
{
    int n = blockIdx.x * 256 + threadIdx.x;
    if (n >= NN) return;
    const float4* arow = reinterpret_cast<const float4*>(agg2 + (size_t)n * 8);
    const float4* rrow = reinterpret_cast<const float4*>(r2   + (size_t)n * 8);
    float h2[8];
    {
        float4 a0 = arow[0], a1 = arow[1], r0 = rrow[0], r1 = rrow[1];
        h2[0]=a0.x+r0.x+b2[0]; h2[1]=a0.y+r0.y+b2[1];
        h2[2]=a0.z+r0.z+b2[2]; h2[3]=a0.w+r0.w+b2[3];
        h2[4]=a1.x+r1.x+b2[4]; h2[5]=a1.y+r1.y+b2[5];
        h2[6]=a1.z+r1.z+b2[6]; h2[7]=a1.w+r1.w+b2[7];
    }
    float m = h2[0];
#pragma unroll
    for (int j = 1; j < 8; ++j) m = fmaxf(m, h2[j]);
    float sum = 0.f;
#pragma unroll
    for (int j = 0; j < 8; ++j) sum += __expf(h2[j] - m);
    float lse = __logf(sum);
    float eb[8];
#pragma unroll
    for (int j = 0; j < 8; ++j) eb[j] = h2[j] - m - lse;
    float4* eo = reinterpret_cast<float4*>(emb + (size_t)n * 8);
    float4 v0, v1;
    v0.x=eb[0]; v0.y=eb[1]; v0.z=eb[2]; v0.w=eb[3]; eo[0]=v0;
    v1.x=eb[4]; v1.y=eb[5]; v1.z=eb[6]; v1.w=eb[7]; eo[1]=v1;
    float acc = b_lin[0] + x1[n] * W_lin[8];
#pragma unroll
    for (int j = 0; j < 8; ++j) acc += eb[j] * W_lin[j];
    outv[n] = acc > 0.f ? acc : 0.f;
}

// ---------------------------------------------------------------------------
extern "C" void kernel_launch(void* const* d_in, const int* in_sizes, int n_in,
                              void* d_out, int out_size, void* d_ws, size_t ws_size,
                              hipStream_t stream) {
    const float* x      = (const float*)d_in[0];
    const int*   ei     = (const int*)  d_in[1];
    const float* ew     = (const float*)d_in[2];
    const float* x1     = (const float*)d_in[3];
    const float* W1_rel = (const float*)d_in[4];
    const float* b1     = (const float*)d_in[5];
    const float* W1_root= (const float*)d_in[6];
    const float* W2_rel = (const float*)d_in[7];
    const float* b2     = (const float*)d_in[8];
    const float* W2_root= (const float*)d_in[9];
    const float* W_lin  = (const float*)d_in[10];
    const float* b_lin  = (const float*)d_in[11];

    float* ws   = (float*)d_ws;
    float* y1   = ws;                        // N*32
    float* agg1 = y1   + (size_t)NN * 32;    // N*32
    float* y2   = agg1 + (size_t)NN * 32;    // N*8
    float* r2   = y2   + (size_t)NN * 8;     // N*8
    float* agg2 = r2   + (size_t)NN * 8;     // N*8
    int*   counts = (int*)(agg2 + (size_t)NN * 8);  // N
    int*   rowptr = counts + NN;             // N+1
    int*   cursor = rowptr + NN + 1;         // N
    int2*  packed = (int2*)(cursor + NN + 3);// NE int2 (aligned to 16B region)

    float* outv = (float*)d_out;             // N   (output 0)
    float* emb  = outv + NN;                 // N*8 (output 1)

    hipMemsetAsync(counts, 0, (size_t)NN * sizeof(int), stream);

    int nbN = (NN + 255) / 256;
    int nbE = (NE + 255) / 256;

    k_hist<<<nbE, 256, 0, stream>>>(ei, counts);
    k_scan<<<1, 1024, 0, stream>>>(counts, rowptr, cursor);
    k_scatter<<<nbE, 256, 0, stream>>>(ei, ew, cursor, packed);
    k_transform1<<<nbN, 256, 0, stream>>>(x, W1_rel, y1);
    k_reduce1<<<(NN * 8 + 255) / 256, 256, 0, stream>>>(rowptr, packed, y1, agg1);
    k_node1<<<nbN, 256, 0, stream>>>(x, agg1, W1_root, b1, W2_rel, W2_root, y2, r2);
    k_reduce2<<<(NN * 2 + 255) / 256, 256, 0, stream>>>(rowptr, packed, y2, agg2);
    k_final<<<nbN, 256, 0, stream>>>(agg2, r2, x1, b2, W_lin, b_lin, outv, emb);
}